// Round 1
// baseline (2332.499 us; speedup 1.0000x reference)
//
#include <hip/hip_runtime.h>

#define N_NODES 50000
#define N_EDGES 500000
#define S_CH 64
#define V_CH 32
#define R_CH 32
#define MLPW 128
#define DIN 161          // 2*64 + 32 + 1
#define OUTC 320         // 32 + 96*3
#define EB 64            // edges per block
#define ASTR 68          // LDS stride (pad, multiple of 4 for b128 alignment)
#define HSTR 68

#define INV_SQ3 0.57735026918962576f
#define INV_SQ2 0.70710678118654752f
#define INV_AVG 0.1f

// row-dependent XOR swizzle on the edge index (granularity 4) to spread
// H-writes (j0 = 8*jj, stride 68: 8*68 == 0 mod 32 banks) across bank quads.
#define ESWZ(row, e) ((e) ^ ((((row) >> 3) & 7) << 2))

__device__ __forceinline__ float silu_f(float x) {
    return x * (1.0f / (1.0f + __expf(-x)));
}

__global__ __launch_bounds__(256, 2)
void fused_mpconv_kernel(const float* __restrict__ node_scalars,
                         const float* __restrict__ node_vectors,
                         const float* __restrict__ edge_vec,
                         const float* __restrict__ sef,
                         const float* __restrict__ lengths,
                         const int* __restrict__ senders,
                         const int* __restrict__ receivers,
                         const float* __restrict__ W1, const float* __restrict__ b1,
                         const float* __restrict__ W2, const float* __restrict__ b2,
                         const float* __restrict__ W3, const float* __restrict__ b3,
                         float* __restrict__ out)
{
    __shared__ float A[DIN][ASTR];   // mlp_in^T; rows 64..159 become v_snd later
    __shared__ float H[MLPW][HSTR];  // hidden / mix, transposed [j][e], e swizzled
    __shared__ float evl[3][EB];
    __shared__ int sidx_l[EB];
    __shared__ int ridx_l[EB];

    const int t   = threadIdx.x;
    const int e   = t & 63;
    const int sub = t >> 6;                    // 0..3
    const int eg  = blockIdx.x * EB + e;
    const bool ve = (eg < N_EDGES);

    if (sub == 0)      sidx_l[e] = ve ? senders[eg] : 0;
    else if (sub == 1) ridx_l[e] = ve ? receivers[eg] : 0;
    else if (sub == 2) {
        evl[0][e] = ve ? edge_vec[(size_t)eg * 3 + 0] : 0.f;
        evl[1][e] = ve ? edge_vec[(size_t)eg * 3 + 1] : 0.f;
        evl[2][e] = ve ? edge_vec[(size_t)eg * 3 + 2] : 0.f;
    }
    __syncthreads();

    // ---- stage mlp_in^T into A ----
    {
        const int si = sidx_l[e];
        const int ri = ridx_l[e];
        for (int i = sub; i < DIN; i += 4) {
            float v = 0.f;
            if (ve) {
                if (i < S_CH)                 v = node_scalars[(size_t)si * S_CH + i];
                else if (i < 2 * S_CH)        v = node_scalars[(size_t)ri * S_CH + (i - S_CH)];
                else if (i < 2 * S_CH + R_CH) v = sef[(size_t)eg * R_CH + (i - 2 * S_CH)];
                else                          v = lengths[eg];
            }
            A[i][e] = v;
        }
    }
    __syncthreads();

    const int jj = t & 15;
    const int j0 = jj * 8;          // 8 output cols per thread
    const int e0 = (t >> 4) * 4;    // 4 edges per thread

    float acc[4][8];

    // ---------- layer 1: h1 = silu(A^T @ W1 + b1) ----------
    #pragma unroll
    for (int ee = 0; ee < 4; ++ee)
        #pragma unroll
        for (int cc = 0; cc < 8; ++cc) acc[ee][cc] = 0.f;

    for (int i = 0; i < DIN; ++i) {
        const float4 a  = *(const float4*)&A[i][e0];
        const float4 w0 = *(const float4*)&W1[(size_t)i * MLPW + j0];
        const float4 w1 = *(const float4*)&W1[(size_t)i * MLPW + j0 + 4];
        const float av[4] = {a.x, a.y, a.z, a.w};
        const float wv[8] = {w0.x, w0.y, w0.z, w0.w, w1.x, w1.y, w1.z, w1.w};
        #pragma unroll
        for (int ee = 0; ee < 4; ++ee)
            #pragma unroll
            for (int cc = 0; cc < 8; ++cc)
                acc[ee][cc] = fmaf(av[ee], wv[cc], acc[ee][cc]);
    }
    __syncthreads();   // all layer-1 reads of A complete

    #pragma unroll
    for (int cc = 0; cc < 8; ++cc) {
        const float b = b1[j0 + cc];
        float4 hv;
        hv.x = silu_f(acc[0][cc] + b);
        hv.y = silu_f(acc[1][cc] + b);
        hv.z = silu_f(acc[2][cc] + b);
        hv.w = silu_f(acc[3][cc] + b);
        *(float4*)&H[j0 + cc][ESWZ(j0 + cc, e0)] = hv;
    }
    // stage v_snd into A rows 64..159 (those rows are dead now)
    {
        const int si = sidx_l[e];
        for (int i = 64 + sub; i < 160; i += 4)
            A[i][e] = ve ? node_vectors[(size_t)si * (V_CH * 3) + (i - 64)] : 0.f;
    }
    __syncthreads();

    // ---------- layer 2: h2 = silu(h1 @ W2 + b2) ----------
    #pragma unroll
    for (int ee = 0; ee < 4; ++ee)
        #pragma unroll
        for (int cc = 0; cc < 8; ++cc) acc[ee][cc] = 0.f;

    for (int i = 0; i < MLPW; ++i) {
        const float4 a  = *(const float4*)&H[i][ESWZ(i, e0)];
        const float4 w0 = *(const float4*)&W2[(size_t)i * MLPW + j0];
        const float4 w1 = *(const float4*)&W2[(size_t)i * MLPW + j0 + 4];
        const float av[4] = {a.x, a.y, a.z, a.w};
        const float wv[8] = {w0.x, w0.y, w0.z, w0.w, w1.x, w1.y, w1.z, w1.w};
        #pragma unroll
        for (int ee = 0; ee < 4; ++ee)
            #pragma unroll
            for (int cc = 0; cc < 8; ++cc)
                acc[ee][cc] = fmaf(av[ee], wv[cc], acc[ee][cc]);
    }
    __syncthreads();   // all layer-2 reads of H complete

    #pragma unroll
    for (int cc = 0; cc < 8; ++cc) {
        const float b = b2[j0 + cc];
        float4 hv;
        hv.x = silu_f(acc[0][cc] + b);
        hv.y = silu_f(acc[1][cc] + b);
        hv.z = silu_f(acc[2][cc] + b);
        hv.w = silu_f(acc[3][cc] + b);
        *(float4*)&H[j0 + cc][ESWZ(j0 + cc, e0)] = hv;
    }
    __syncthreads();

    // ---------- layer 3: mix = h2 @ W3 + b3 ----------
    #pragma unroll
    for (int ee = 0; ee < 4; ++ee)
        #pragma unroll
        for (int cc = 0; cc < 8; ++cc) acc[ee][cc] = 0.f;

    for (int i = 0; i < MLPW; ++i) {
        const float4 a  = *(const float4*)&H[i][ESWZ(i, e0)];
        const float4 w0 = *(const float4*)&W3[(size_t)i * MLPW + j0];
        const float4 w1 = *(const float4*)&W3[(size_t)i * MLPW + j0 + 4];
        const float av[4] = {a.x, a.y, a.z, a.w};
        const float wv[8] = {w0.x, w0.y, w0.z, w0.w, w1.x, w1.y, w1.z, w1.w};
        #pragma unroll
        for (int ee = 0; ee < 4; ++ee)
            #pragma unroll
            for (int cc = 0; cc < 8; ++cc)
                acc[ee][cc] = fmaf(av[ee], wv[cc], acc[ee][cc]);
    }
    __syncthreads();   // all layer-3 reads of H complete

    #pragma unroll
    for (int cc = 0; cc < 8; ++cc) {
        const float b = b3[j0 + cc];
        float4 hv;
        hv.x = acc[0][cc] + b;
        hv.y = acc[1][cc] + b;
        hv.z = acc[2][cc] + b;
        hv.w = acc[3][cc] + b;
        *(float4*)&H[j0 + cc][ESWZ(j0 + cc, e0)] = hv;   // H now holds mix
    }
    __syncthreads();

    // ---------- messages + atomic scatter ----------
    // 4 threads per edge; thread r covers cols r, r+4, ..., r+316
    {
        const int me  = t >> 2;
        const int r   = t & 3;
        const int eg2 = blockIdx.x * EB + me;
        if (eg2 < N_EDGES) {
            const int row = ridx_l[me];
            const float evx = evl[0][me], evy = evl[1][me], evz = evl[2][me];
            float* orow = out + (size_t)row * OUTC;
            for (int col = r; col < OUTC; col += 4) {
                float val;
                if (col < V_CH) {
                    const int c = col;
                    const float vx = A[64 + 3 * c + 0][me];
                    const float vy = A[64 + 3 * c + 1][me];
                    const float vz = A[64 + 3 * c + 2][me];
                    const float g  = H[c][ESWZ(c, me)];
                    val = (vx * evx + vy * evy + vz * evz) * INV_SQ3 * g;
                } else {
                    const int idx = col - V_CH;
                    const int k   = idx / 3;
                    const int d   = idx - 3 * k;
                    const float g = H[V_CH + k][ESWZ(V_CH + k, me)];
                    if (k < S_CH) {
                        const float evd = (d == 0) ? evx : ((d == 1) ? evy : evz);
                        val = A[k][me] * evd * g;
                    } else {
                        const int c = k - S_CH;
                        const float vx = A[64 + 3 * c + 0][me];
                        const float vy = A[64 + 3 * c + 1][me];
                        const float vz = A[64 + 3 * c + 2][me];
                        float cr;
                        if (d == 0)      cr = vy * evz - vz * evy;
                        else if (d == 1) cr = vz * evx - vx * evz;
                        else             cr = vx * evy - vy * evx;
                        val = cr * INV_SQ2 * g;
                    }
                }
                atomicAdd(&orow[col], val * INV_AVG);
            }
        }
    }
}

extern "C" void kernel_launch(void* const* d_in, const int* in_sizes, int n_in,
                              void* d_out, int out_size, void* d_ws, size_t ws_size,
                              hipStream_t stream) {
    (void)in_sizes; (void)n_in; (void)d_ws; (void)ws_size;
    const float* node_scalars = (const float*)d_in[0];
    const float* node_vectors = (const float*)d_in[1];
    const float* edge_vec     = (const float*)d_in[2];
    const float* sef          = (const float*)d_in[3];
    const float* lengths      = (const float*)d_in[4];
    const int*   senders      = (const int*)d_in[5];
    const int*   receivers    = (const int*)d_in[6];
    const float* W1 = (const float*)d_in[7];
    const float* b1 = (const float*)d_in[8];
    const float* W2 = (const float*)d_in[9];
    const float* b2 = (const float*)d_in[10];
    const float* W3 = (const float*)d_in[11];
    const float* b3 = (const float*)d_in[12];
    float* out = (float*)d_out;

    hipMemsetAsync(out, 0, (size_t)out_size * sizeof(float), stream);

    const int nblk = (N_EDGES + EB - 1) / EB;
    fused_mpconv_kernel<<<nblk, 256, 0, stream>>>(
        node_scalars, node_vectors, edge_vec, sef, lengths,
        senders, receivers, W1, b1, W2, b2, W3, b3, out);
}

// Round 2
// 2098.369 us; speedup vs baseline: 1.1116x; 1.1116x over previous
//
#include <hip/hip_runtime.h>

#define N_EDGES 500000
#define EB 64
#define KP1 200          // A row stride (bf16 elems): 400B/row, uniform bank quads
#define KH  136          // H row stride: 272B/row
#define KV  104          // VS row stride: 208B/row
#define WTS 40           // Wt row stride: 80B/row -> (5n+g)%8 uniform quads, 16B aligned
#define OUTC 320
#define INV_SQ3 0.57735026918962576f
#define INV_SQ2 0.70710678118654752f
#define INV_AVG 0.1f

typedef short bf16x8 __attribute__((ext_vector_type(8)));
typedef unsigned short u16;
typedef u16 u16x8 __attribute__((ext_vector_type(8)));
typedef float f32x16 __attribute__((ext_vector_type(16)));

__device__ __forceinline__ float bf2f(u16 h) {
    union { unsigned u; float f; } x; x.u = ((unsigned)h) << 16; return x.f;
}
__device__ __forceinline__ u16 f2bf(float f) {   // round-to-nearest-even
    unsigned u = __builtin_bit_cast(unsigned, f);
    u += 0x7FFFu + ((u >> 16) & 1u);
    return (u16)(u >> 16);
}
__device__ __forceinline__ float fsilu(float x) {
    return x * __builtin_amdgcn_rcpf(1.f + __expf(-x));
}

__device__ __forceinline__ void stage16(const float* g, u16* l, bool v) {
    float4 a0, a1, a2, a3;
    const float4 z = make_float4(0.f, 0.f, 0.f, 0.f);
    if (v) { a0 = *(const float4*)(g);     a1 = *(const float4*)(g + 4);
             a2 = *(const float4*)(g + 8); a3 = *(const float4*)(g + 12); }
    else   { a0 = z; a1 = z; a2 = z; a3 = z; }
    u16x8 p0 = { f2bf(a0.x), f2bf(a0.y), f2bf(a0.z), f2bf(a0.w),
                 f2bf(a1.x), f2bf(a1.y), f2bf(a1.z), f2bf(a1.w) };
    u16x8 p1 = { f2bf(a2.x), f2bf(a2.y), f2bf(a2.z), f2bf(a2.w),
                 f2bf(a3.x), f2bf(a3.y), f2bf(a3.z), f2bf(a3.w) };
    *(u16x8*)(l) = p0; *(u16x8*)(l + 8) = p1;
}
__device__ __forceinline__ void stage8(const float* g, u16* l, bool v) {
    float4 a0, a1;
    const float4 z = make_float4(0.f, 0.f, 0.f, 0.f);
    if (v) { a0 = *(const float4*)(g); a1 = *(const float4*)(g + 4); }
    else   { a0 = z; a1 = z; }
    u16x8 p0 = { f2bf(a0.x), f2bf(a0.y), f2bf(a0.z), f2bf(a0.w),
                 f2bf(a1.x), f2bf(a1.y), f2bf(a1.z), f2bf(a1.w) };
    *(u16x8*)(l) = p0;
}

__global__ __launch_bounds__(256, 2)
void fused_mpconv_mfma(const float* __restrict__ node_scalars,
                       const float* __restrict__ node_vectors,
                       const float* __restrict__ edge_vec,
                       const float* __restrict__ sef,
                       const float* __restrict__ lengths,
                       const int* __restrict__ senders,
                       const int* __restrict__ receivers,
                       const float* __restrict__ W1, const float* __restrict__ b1,
                       const float* __restrict__ W2, const float* __restrict__ b2,
                       const float* __restrict__ W3, const float* __restrict__ b3,
                       float* __restrict__ out)
{
    __shared__ u16 A [EB * KP1];      // mlp_in  [edge][k0..160], zero-padded to 200
    __shared__ u16 VS[EB * KV];       // v_snd   [edge][96]
    __shared__ u16 Hb[EB * KH];       // h1 -> h2 -> mix  [edge][128]
    __shared__ u16 Wt[2][128 * WTS];  // W^T chunk dbuf: [n][k_local 0..15]
    __shared__ float evl[3][EB];
    __shared__ int sidx[EB], ridx[EB];

    const int t = threadIdx.x;
    const int ebase = blockIdx.x * EB;

    {   const int e = t & 63, sub = t >> 6;
        const int eg = ebase + e; const bool ve = eg < N_EDGES;
        if (sub == 0)      sidx[e] = ve ? senders[eg] : 0;
        else if (sub == 1) ridx[e] = ve ? receivers[eg] : 0;
        else if (sub == 2) {
            evl[0][e] = ve ? edge_vec[(size_t)eg * 3 + 0] : 0.f;
            evl[1][e] = ve ? edge_vec[(size_t)eg * 3 + 1] : 0.f;
            evl[2][e] = ve ? edge_vec[(size_t)eg * 3 + 2] : 0.f;
        }
    }
    __syncthreads();

    // ---- gather-stage inputs as bf16 (A = mlp_in^T-ish [edge][k], VS = v_snd) ----
    {   const int me = t >> 2, q = t & 3;
        const int eg = ebase + me; const bool ve = eg < N_EDGES;
        const int si = sidx[me], ri = ridx[me];
        u16* Ar = A + me * KP1;
        stage16(node_scalars + (size_t)si * 64 + q * 16, Ar + q * 16,       ve);
        stage16(node_scalars + (size_t)ri * 64 + q * 16, Ar + 64 + q * 16,  ve);
        stage8 (sef          + (size_t)eg * 32 + q * 8,  Ar + 128 + q * 8,  ve);
        u16x8 zz = (u16x8)0;
        *(u16x8*)(Ar + 160 + q * 8) = zz;          // zero pad k 160..191
        if (q == 0) *(u16x8*)(Ar + 192) = zz;      // pad 192..199
        stage16(node_vectors + (size_t)si * 96 + q * 24,      VS + me * KV + q * 24,      ve);
        stage8 (node_vectors + (size_t)si * 96 + q * 24 + 16, VS + me * KV + q * 24 + 16, ve);
        if (q == 0) Ar[160] = f2bf(ve ? lengths[eg] : 0.f);   // after zero write, same thread
    }
    __syncthreads();

    const int w  = t >> 6, l = t & 63;
    const int lr = l & 31;        // row-in-tile (A) / col (B,D)
    const int lg = l >> 5;        // k-granule
    const int m0 = (w >> 1) * 32; // edge base of this wave's tile
    const int n0 = (w & 1) * 64;  // col  base

    f32x16 acc0, acc1;
    const int n  = t & 127, ph = t >> 7;

    // ---- one MLP layer: acc = Asrc[64 x K] @ Wg[K x 128] (this wave's 32x64 slice) ----
    auto run_layer = [&](const u16* Asrc, int astr, const float* Wg, int Kr, int nsteps,
                         f32x16& a0, f32x16& a1) {
        #pragma unroll
        for (int i = 0; i < 16; ++i) { a0[i] = 0.f; a1[i] = 0.f; }
        // stage chunk 0 (transpose W rows -> Wt[n][k_local], bf16 pairs)
        #pragma unroll
        for (int i = 0; i < 4; ++i) {
            int kl = (i * 2 + ph) * 2;
            float v0 = (kl     < Kr) ? Wg[(size_t)kl * 128 + n]       : 0.f;
            float v1 = (kl + 1 < Kr) ? Wg[(size_t)(kl + 1) * 128 + n] : 0.f;
            unsigned pk = ((unsigned)f2bf(v1) << 16) | (unsigned)f2bf(v0);
            *(unsigned*)&Wt[0][n * WTS + kl] = pk;
        }
        __syncthreads();
        const u16* ap = Asrc + (m0 + lr) * astr + lg * 8;
        for (int ks = 0; ks < nsteps; ++ks) {
            const int cur = ks & 1;
            float v0[4], v1[4];
            const int kb = (ks + 1) * 16;
            if (ks + 1 < nsteps) {
                #pragma unroll
                for (int i = 0; i < 4; ++i) {
                    int kg = kb + (i * 2 + ph) * 2;
                    v0[i] = (kg     < Kr) ? Wg[(size_t)kg * 128 + n]       : 0.f;
                    v1[i] = (kg + 1 < Kr) ? Wg[(size_t)(kg + 1) * 128 + n] : 0.f;
                }
            }
            bf16x8 af = *(const bf16x8*)(ap + ks * 16);
            bf16x8 bf0 = *(const bf16x8*)(&Wt[cur][(n0      + lr) * WTS + lg * 8]);
            bf16x8 bf1 = *(const bf16x8*)(&Wt[cur][(n0 + 32 + lr) * WTS + lg * 8]);
            a0 = __builtin_amdgcn_mfma_f32_32x32x16_bf16(af, bf0, a0, 0, 0, 0);
            a1 = __builtin_amdgcn_mfma_f32_32x32x16_bf16(af, bf1, a1, 0, 0, 0);
            if (ks + 1 < nsteps) {
                #pragma unroll
                for (int i = 0; i < 4; ++i) {
                    int kl = (i * 2 + ph) * 2;
                    unsigned pk = ((unsigned)f2bf(v1[i]) << 16) | (unsigned)f2bf(v0[i]);
                    *(unsigned*)&Wt[cur ^ 1][n * WTS + kl] = pk;
                }
            }
            __syncthreads();
        }
    };

    // ---------- layer 1 ----------
    run_layer(A, KP1, W1, 161, 11, acc0, acc1);
    {   const float bv0 = b1[n0 + lr], bv1 = b1[n0 + 32 + lr];
        #pragma unroll
        for (int r = 0; r < 16; ++r) {
            const int row = (r & 3) + 8 * (r >> 2) + 4 * lg;   // verified C/D layout
            Hb[(m0 + row) * KH + n0 + lr]      = f2bf(fsilu(acc0[r] + bv0));
            Hb[(m0 + row) * KH + n0 + 32 + lr] = f2bf(fsilu(acc1[r] + bv1));
        }
    }
    __syncthreads();

    // ---------- layer 2 ----------
    run_layer(Hb, KH, W2, 128, 8, acc0, acc1);
    __syncthreads();
    {   const float bv0 = b2[n0 + lr], bv1 = b2[n0 + 32 + lr];
        #pragma unroll
        for (int r = 0; r < 16; ++r) {
            const int row = (r & 3) + 8 * (r >> 2) + 4 * lg;
            Hb[(m0 + row) * KH + n0 + lr]      = f2bf(fsilu(acc0[r] + bv0));
            Hb[(m0 + row) * KH + n0 + 32 + lr] = f2bf(fsilu(acc1[r] + bv1));
        }
    }
    __syncthreads();

    // ---------- layer 3 (mix, no activation) ----------
    run_layer(Hb, KH, W3, 128, 8, acc0, acc1);
    __syncthreads();
    {   const float bv0 = b3[n0 + lr], bv1 = b3[n0 + 32 + lr];
        #pragma unroll
        for (int r = 0; r < 16; ++r) {
            const int row = (r & 3) + 8 * (r >> 2) + 4 * lg;
            Hb[(m0 + row) * KH + n0 + lr]      = f2bf(acc0[r] + bv0);
            Hb[(m0 + row) * KH + n0 + 32 + lr] = f2bf(acc1[r] + bv1);
        }
    }
    __syncthreads();

    // ---------- messages + atomic scatter (4 threads/edge) ----------
    {   const int me = t >> 2, r = t & 3;
        const int eg2 = ebase + me;
        if (eg2 < N_EDGES) {
            const int row = ridx[me];
            const float evx = evl[0][me], evy = evl[1][me], evz = evl[2][me];
            float* orow = out + (size_t)row * OUTC;
            const u16* Ar = A  + me * KP1;
            const u16* Vr = VS + me * KV;
            const u16* Hr = Hb + me * KH;
            for (int col = r; col < OUTC; col += 4) {
                float val;
                if (col < 32) {
                    const int c = col;
                    const float vx = bf2f(Vr[3 * c]), vy = bf2f(Vr[3 * c + 1]), vz = bf2f(Vr[3 * c + 2]);
                    val = (vx * evx + vy * evy + vz * evz) * INV_SQ3 * bf2f(Hr[c]);
                } else {
                    const int idx = col - 32;
                    const int k = idx / 3;
                    const int d = idx - 3 * k;
                    const float g = bf2f(Hr[32 + k]);
                    if (k < 64) {
                        const float evd = (d == 0) ? evx : ((d == 1) ? evy : evz);
                        val = bf2f(Ar[k]) * evd * g;
                    } else {
                        const int c = k - 64;
                        const float vx = bf2f(Vr[3 * c]), vy = bf2f(Vr[3 * c + 1]), vz = bf2f(Vr[3 * c + 2]);
                        float cr;
                        if (d == 0)      cr = vy * evz - vz * evy;
                        else if (d == 1) cr = vz * evx - vx * evz;
                        else             cr = vx * evy - vy * evx;
                        val = cr * INV_SQ2 * g;
                    }
                }
                atomicAdd(&orow[col], val * INV_AVG);
            }
        }
    }
}

extern "C" void kernel_launch(void* const* d_in, const int* in_sizes, int n_in,
                              void* d_out, int out_size, void* d_ws, size_t ws_size,
                              hipStream_t stream) {
    (void)in_sizes; (void)n_in; (void)d_ws; (void)ws_size;
    const float* node_scalars = (const float*)d_in[0];
    const float* node_vectors = (const float*)d_in[1];
    const float* edge_vec     = (const float*)d_in[2];
    const float* sef          = (const float*)d_in[3];
    const float* lengths      = (const float*)d_in[4];
    const int*   senders      = (const int*)d_in[5];
    const int*   receivers    = (const int*)d_in[6];
    const float* W1 = (const float*)d_in[7];
    const float* b1 = (const float*)d_in[8];
    const float* W2 = (const float*)d_in[9];
    const float* b2 = (const float*)d_in[10];
    const float* W3 = (const float*)d_in[11];
    const float* b3 = (const float*)d_in[12];
    float* out = (float*)d_out;

    hipMemsetAsync(out, 0, (size_t)out_size * sizeof(float), stream);

    const int nblk = (N_EDGES + EB - 1) / EB;
    fused_mpconv_mfma<<<nblk, 256, 0, stream>>>(
        node_scalars, node_vectors, edge_vec, sef, lengths,
        senders, receivers, W1, b1, W2, b2, W3, b3, out);
}

// Round 3
// 937.404 us; speedup vs baseline: 2.4883x; 2.2385x over previous
//
#include <hip/hip_runtime.h>

#define N_NODES 50000
#define N_EDGES 500000
#define EB 64
#define KP1 200          // A row stride (bf16 elems)
#define KH  136          // H row stride
#define KV  104          // VS row stride (fallback kernel only)
#define WTS 40           // Wt row stride
#define OUTC 320
#define MIXROWS 500032   // 7813 * 64
#define NBLK1 49         // ceil(50000/1024) scan level-1 blocks
#define INV_SQ3 0.57735026918962576f
#define INV_SQ2 0.70710678118654752f
#define INV_AVG 0.1f

typedef short bf16x8 __attribute__((ext_vector_type(8)));
typedef unsigned short u16;
typedef u16 u16x8 __attribute__((ext_vector_type(8)));
typedef float f32x16 __attribute__((ext_vector_type(16)));

__device__ __forceinline__ float bf2f(u16 h) {
    union { unsigned u; float f; } x; x.u = ((unsigned)h) << 16; return x.f;
}
__device__ __forceinline__ u16 f2bf(float f) {   // RNE
    unsigned u = __builtin_bit_cast(unsigned, f);
    u += 0x7FFFu + ((u >> 16) & 1u);
    return (u16)(u >> 16);
}
__device__ __forceinline__ float fsilu(float x) {
    return x * __builtin_amdgcn_rcpf(1.f + __expf(-x));
}

__device__ __forceinline__ void stage16(const float* g, u16* l, bool v) {
    float4 a0, a1, a2, a3;
    const float4 z = make_float4(0.f, 0.f, 0.f, 0.f);
    if (v) { a0 = *(const float4*)(g);     a1 = *(const float4*)(g + 4);
             a2 = *(const float4*)(g + 8); a3 = *(const float4*)(g + 12); }
    else   { a0 = z; a1 = z; a2 = z; a3 = z; }
    u16x8 p0 = { f2bf(a0.x), f2bf(a0.y), f2bf(a0.z), f2bf(a0.w),
                 f2bf(a1.x), f2bf(a1.y), f2bf(a1.z), f2bf(a1.w) };
    u16x8 p1 = { f2bf(a2.x), f2bf(a2.y), f2bf(a2.z), f2bf(a2.w),
                 f2bf(a3.x), f2bf(a3.y), f2bf(a3.z), f2bf(a3.w) };
    *(u16x8*)(l) = p0; *(u16x8*)(l + 8) = p1;
}
__device__ __forceinline__ void stage8(const float* g, u16* l, bool v) {
    float4 a0, a1;
    const float4 z = make_float4(0.f, 0.f, 0.f, 0.f);
    if (v) { a0 = *(const float4*)(g); a1 = *(const float4*)(g + 4); }
    else   { a0 = z; a1 = z; }
    u16x8 p0 = { f2bf(a0.x), f2bf(a0.y), f2bf(a0.z), f2bf(a0.w),
                 f2bf(a1.x), f2bf(a1.y), f2bf(a1.z), f2bf(a1.w) };
    *(u16x8*)(l) = p0;
}

// ==================== CSR build ====================

__global__ void hist_kernel(const int* __restrict__ recv, int* __restrict__ counts) {
    const int e = blockIdx.x * 256 + threadIdx.x;
    if (e < N_EDGES) atomicAdd(&counts[recv[e]], 1);
}

// level-1: each block scans 1024 counts -> exclusive prefix into rowp, total into partials
__global__ __launch_bounds__(256) void scan_k1(const int* __restrict__ counts,
                                               int* __restrict__ rowp,
                                               int* __restrict__ partials) {
    __shared__ int sd[256];
    const int t = threadIdx.x;
    const int base = blockIdx.x * 1024 + t * 4;
    int c0 = 0, c1 = 0, c2 = 0, c3 = 0;
    if (base + 3 < N_NODES) {
        int4 v = *(const int4*)&counts[base];
        c0 = v.x; c1 = v.y; c2 = v.z; c3 = v.w;
    } else {
        if (base     < N_NODES) c0 = counts[base];
        if (base + 1 < N_NODES) c1 = counts[base + 1];
        if (base + 2 < N_NODES) c2 = counts[base + 2];
        if (base + 3 < N_NODES) c3 = counts[base + 3];
    }
    const int T = c0 + c1 + c2 + c3;
    sd[t] = T; __syncthreads();
    for (int off = 1; off < 256; off <<= 1) {
        int v = (t >= off) ? sd[t - off] : 0;
        __syncthreads();
        sd[t] += v;
        __syncthreads();
    }
    const int excl = sd[t] - T;
    if (base     < N_NODES) rowp[base]     = excl;
    if (base + 1 < N_NODES) rowp[base + 1] = excl + c0;
    if (base + 2 < N_NODES) rowp[base + 2] = excl + c0 + c1;
    if (base + 3 < N_NODES) rowp[base + 3] = excl + c0 + c1 + c2;
    if (t == 255) partials[blockIdx.x] = sd[255];
}

// level-2: exclusive scan of NBLK1 partials (single block of 64)
__global__ __launch_bounds__(64) void scan_k2(int* __restrict__ partials) {
    __shared__ int sd[64];
    const int t = threadIdx.x;
    const int v0 = (t < NBLK1) ? partials[t] : 0;
    sd[t] = v0; __syncthreads();
    for (int off = 1; off < 64; off <<= 1) {
        int v = (t >= off) ? sd[t - off] : 0;
        __syncthreads();
        sd[t] += v;
        __syncthreads();
    }
    if (t < NBLK1) partials[t] = sd[t] - v0;
}

// level-3: add block offsets, copy cursors, set rowp[N]=E
__global__ __launch_bounds__(256) void scan_k3(int* __restrict__ rowp,
                                               const int* __restrict__ partials,
                                               int* __restrict__ cursors) {
    const int add = partials[blockIdx.x];
    const int base = blockIdx.x * 1024 + threadIdx.x * 4;
    #pragma unroll
    for (int i = 0; i < 4; ++i) {
        const int idx = base + i;
        if (idx < N_NODES) {
            const int v = rowp[idx] + add;
            rowp[idx] = v;
            cursors[idx] = v;
        }
    }
    if (blockIdx.x == 0 && threadIdx.x == 0) rowp[N_NODES] = N_EDGES;
}

__global__ void fill_kernel(const int* __restrict__ recv,
                            int* __restrict__ cursors, int* __restrict__ elist) {
    const int e = blockIdx.x * 256 + threadIdx.x;
    if (e < N_EDGES) {
        const int r = recv[e];
        const int pos = atomicAdd(&cursors[r], 1);
        elist[pos] = e;
    }
}

// ==================== phase E: fused MLP -> mix (bf16) ====================

__global__ __launch_bounds__(256, 2)
void mlp_mix_kernel(const float* __restrict__ node_scalars,
                    const float* __restrict__ sef,
                    const float* __restrict__ lengths,
                    const int* __restrict__ senders,
                    const int* __restrict__ receivers,
                    const float* __restrict__ W1, const float* __restrict__ b1,
                    const float* __restrict__ W2, const float* __restrict__ b2,
                    const float* __restrict__ W3, const float* __restrict__ b3,
                    u16* __restrict__ mixws)
{
    __shared__ u16 A [EB * KP1];
    __shared__ u16 Hb[EB * KH];
    __shared__ u16 Wt[2][128 * WTS];
    __shared__ int sidx[EB], ridx[EB];

    const int t = threadIdx.x;
    const int ebase = blockIdx.x * EB;

    {   const int e = t & 63, sub = t >> 6;
        const int eg = ebase + e; const bool ve = eg < N_EDGES;
        if (sub == 0)      sidx[e] = ve ? senders[eg] : 0;
        else if (sub == 1) ridx[e] = ve ? receivers[eg] : 0;
    }
    __syncthreads();

    {   const int me = t >> 2, q = t & 3;
        const int eg = ebase + me; const bool ve = eg < N_EDGES;
        const int si = sidx[me], ri = ridx[me];
        u16* Ar = A + me * KP1;
        stage16(node_scalars + (size_t)si * 64 + q * 16, Ar + q * 16,       ve);
        stage16(node_scalars + (size_t)ri * 64 + q * 16, Ar + 64 + q * 16,  ve);
        stage8 (sef          + (size_t)eg * 32 + q * 8,  Ar + 128 + q * 8,  ve);
        u16x8 zz = (u16x8)0;
        *(u16x8*)(Ar + 160 + q * 8) = zz;
        if (q == 0) *(u16x8*)(Ar + 192) = zz;
        if (q == 0) Ar[160] = f2bf(ve ? lengths[eg] : 0.f);
    }
    __syncthreads();

    const int w  = t >> 6, l = t & 63;
    const int lr = l & 31;
    const int lg = l >> 5;
    const int m0 = (w >> 1) * 32;
    const int n0 = (w & 1) * 64;

    f32x16 acc0, acc1;
    const int n  = t & 127, ph = t >> 7;

    auto run_layer = [&](const u16* Asrc, int astr, const float* Wg, int Kr, int nsteps,
                         f32x16& a0, f32x16& a1) {
        #pragma unroll
        for (int i = 0; i < 16; ++i) { a0[i] = 0.f; a1[i] = 0.f; }
        #pragma unroll
        for (int i = 0; i < 4; ++i) {
            int kl = (i * 2 + ph) * 2;
            float v0 = (kl     < Kr) ? Wg[(size_t)kl * 128 + n]       : 0.f;
            float v1 = (kl + 1 < Kr) ? Wg[(size_t)(kl + 1) * 128 + n] : 0.f;
            unsigned pk = ((unsigned)f2bf(v1) << 16) | (unsigned)f2bf(v0);
            *(unsigned*)&Wt[0][n * WTS + kl] = pk;
        }
        __syncthreads();
        const u16* ap = Asrc + (m0 + lr) * astr + lg * 8;
        for (int ks = 0; ks < nsteps; ++ks) {
            const int cur = ks & 1;
            float v0[4], v1[4];
            const int kb = (ks + 1) * 16;
            if (ks + 1 < nsteps) {
                #pragma unroll
                for (int i = 0; i < 4; ++i) {
                    int kg = kb + (i * 2 + ph) * 2;
                    v0[i] = (kg     < Kr) ? Wg[(size_t)kg * 128 + n]       : 0.f;
                    v1[i] = (kg + 1 < Kr) ? Wg[(size_t)(kg + 1) * 128 + n] : 0.f;
                }
            }
            bf16x8 af = *(const bf16x8*)(ap + ks * 16);
            bf16x8 bf0 = *(const bf16x8*)(&Wt[cur][(n0      + lr) * WTS + lg * 8]);
            bf16x8 bf1 = *(const bf16x8*)(&Wt[cur][(n0 + 32 + lr) * WTS + lg * 8]);
            a0 = __builtin_amdgcn_mfma_f32_32x32x16_bf16(af, bf0, a0, 0, 0, 0);
            a1 = __builtin_amdgcn_mfma_f32_32x32x16_bf16(af, bf1, a1, 0, 0, 0);
            if (ks + 1 < nsteps) {
                #pragma unroll
                for (int i = 0; i < 4; ++i) {
                    int kl = (i * 2 + ph) * 2;
                    unsigned pk = ((unsigned)f2bf(v1[i]) << 16) | (unsigned)f2bf(v0[i]);
                    *(unsigned*)&Wt[cur ^ 1][n * WTS + kl] = pk;
                }
            }
            __syncthreads();
        }
    };

    run_layer(A, KP1, W1, 161, 11, acc0, acc1);
    {   const float bv0 = b1[n0 + lr], bv1 = b1[n0 + 32 + lr];
        #pragma unroll
        for (int r = 0; r < 16; ++r) {
            const int row = (r & 3) + 8 * (r >> 2) + 4 * lg;
            Hb[(m0 + row) * KH + n0 + lr]      = f2bf(fsilu(acc0[r] + bv0));
            Hb[(m0 + row) * KH + n0 + 32 + lr] = f2bf(fsilu(acc1[r] + bv1));
        }
    }
    __syncthreads();

    run_layer(Hb, KH, W2, 128, 8, acc0, acc1);
    __syncthreads();
    {   const float bv0 = b2[n0 + lr], bv1 = b2[n0 + 32 + lr];
        #pragma unroll
        for (int r = 0; r < 16; ++r) {
            const int row = (r & 3) + 8 * (r >> 2) + 4 * lg;
            Hb[(m0 + row) * KH + n0 + lr]      = f2bf(fsilu(acc0[r] + bv0));
            Hb[(m0 + row) * KH + n0 + 32 + lr] = f2bf(fsilu(acc1[r] + bv1));
        }
    }
    __syncthreads();

    run_layer(Hb, KH, W3, 128, 8, acc0, acc1);
    __syncthreads();
    {   const float bv0 = b3[n0 + lr], bv1 = b3[n0 + 32 + lr];
        #pragma unroll
        for (int r = 0; r < 16; ++r) {
            const int row = (r & 3) + 8 * (r >> 2) + 4 * lg;
            Hb[(m0 + row) * KH + n0 + lr]      = f2bf(acc0[r] + bv0);
            Hb[(m0 + row) * KH + n0 + 32 + lr] = f2bf(acc1[r] + bv1);
        }
    }
    __syncthreads();

    // coalesced copy Hb (mix) -> mixws [eg][128]
    #pragma unroll
    for (int p = 0; p < 4; ++p) {
        const int idx = p * 2048 + t * 8;
        const int e   = idx >> 7;
        const int col = idx & 127;
        u16x8 v = *(u16x8*)&Hb[e * KH + col];
        *(u16x8*)&mixws[(size_t)(ebase + e) * 128 + col] = v;
    }
}

// ==================== phase 2: wave-per-node gather ====================

__global__ __launch_bounds__(256)
void node_gather_kernel(const float* __restrict__ node_scalars,
                        const float* __restrict__ node_vectors,
                        const float* __restrict__ edge_vec,
                        const int* __restrict__ senders,
                        const int* __restrict__ rowp,
                        const int* __restrict__ elist,
                        const u16* __restrict__ mixws,
                        float* __restrict__ out)
{
    const int gw = (blockIdx.x * 256 + threadIdx.x) >> 6;   // global wave = node
    const int l  = threadIdx.x & 63;
    if (gw >= N_NODES) return;

    const int rp0 = rowp[gw], rp1 = rowp[gw + 1];

    // per-lane column metadata (fully unrolled -> registers)
    int mode[5], kk[5], dd[5], gi[5];
    #pragma unroll
    for (int cc = 0; cc < 5; ++cc) {
        const int col = 5 * l + cc;
        if (col < 32) { mode[cc] = 0; kk[cc] = col; dd[cc] = 0; gi[cc] = col; }
        else {
            const int idx = col - 32;
            const int k = idx / 3;
            const int d = idx - 3 * k;
            gi[cc] = 32 + k;
            if (k < 64) { mode[cc] = 1; kk[cc] = k;      dd[cc] = d; }
            else        { mode[cc] = 2; kk[cc] = k - 64; dd[cc] = d; }
        }
    }

    float acc[5] = {0.f, 0.f, 0.f, 0.f, 0.f};

    for (int j = rp0; j < rp1; ++j) {
        const int e = elist[j];
        const int s = senders[e];
        const float evx = edge_vec[(size_t)e * 3 + 0];
        const float evy = edge_vec[(size_t)e * 3 + 1];
        const float evz = edge_vec[(size_t)e * 3 + 2];
        const float* ns = node_scalars + (size_t)s * 64;
        const float* nv = node_vectors + (size_t)s * 96;
        const u16*   mg = mixws + (size_t)e * 128;
        #pragma unroll
        for (int cc = 0; cc < 5; ++cc) {
            const float g = bf2f(mg[gi[cc]]);
            float f;
            if (mode[cc] == 0) {
                const int c = kk[cc];
                f = (nv[3 * c] * evx + nv[3 * c + 1] * evy + nv[3 * c + 2] * evz) * INV_SQ3;
            } else if (mode[cc] == 1) {
                const float evd = (dd[cc] == 0) ? evx : ((dd[cc] == 1) ? evy : evz);
                f = ns[kk[cc]] * evd;
            } else {
                const int c = kk[cc];
                const float vx = nv[3 * c], vy = nv[3 * c + 1], vz = nv[3 * c + 2];
                float cr;
                if (dd[cc] == 0)      cr = vy * evz - vz * evy;
                else if (dd[cc] == 1) cr = vz * evx - vx * evz;
                else                  cr = vx * evy - vy * evx;
                f = cr * INV_SQ2;
            }
            acc[cc] = fmaf(f, g, acc[cc]);
        }
    }

    float* orow = out + (size_t)gw * OUTC + 5 * l;
    #pragma unroll
    for (int cc = 0; cc < 5; ++cc) orow[cc] = acc[cc] * INV_AVG;
}

// ==================== fallback: round-2 atomic kernel ====================

__global__ __launch_bounds__(256, 2)
void fused_mpconv_atomic(const float* __restrict__ node_scalars,
                         const float* __restrict__ node_vectors,
                         const float* __restrict__ edge_vec,
                         const float* __restrict__ sef,
                         const float* __restrict__ lengths,
                         const int* __restrict__ senders,
                         const int* __restrict__ receivers,
                         const float* __restrict__ W1, const float* __restrict__ b1,
                         const float* __restrict__ W2, const float* __restrict__ b2,
                         const float* __restrict__ W3, const float* __restrict__ b3,
                         float* __restrict__ out)
{
    __shared__ u16 A [EB * KP1];
    __shared__ u16 VS[EB * KV];
    __shared__ u16 Hb[EB * KH];
    __shared__ u16 Wt[2][128 * WTS];
    __shared__ float evl[3][EB];
    __shared__ int sidx[EB], ridx[EB];

    const int t = threadIdx.x;
    const int ebase = blockIdx.x * EB;

    {   const int e = t & 63, sub = t >> 6;
        const int eg = ebase + e; const bool ve = eg < N_EDGES;
        if (sub == 0)      sidx[e] = ve ? senders[eg] : 0;
        else if (sub == 1) ridx[e] = ve ? receivers[eg] : 0;
        else if (sub == 2) {
            evl[0][e] = ve ? edge_vec[(size_t)eg * 3 + 0] : 0.f;
            evl[1][e] = ve ? edge_vec[(size_t)eg * 3 + 1] : 0.f;
            evl[2][e] = ve ? edge_vec[(size_t)eg * 3 + 2] : 0.f;
        }
    }
    __syncthreads();

    {   const int me = t >> 2, q = t & 3;
        const int eg = ebase + me; const bool ve = eg < N_EDGES;
        const int si = sidx[me], ri = ridx[me];
        u16* Ar = A + me * KP1;
        stage16(node_scalars + (size_t)si * 64 + q * 16, Ar + q * 16,       ve);
        stage16(node_scalars + (size_t)ri * 64 + q * 16, Ar + 64 + q * 16,  ve);
        stage8 (sef          + (size_t)eg * 32 + q * 8,  Ar + 128 + q * 8,  ve);
        u16x8 zz = (u16x8)0;
        *(u16x8*)(Ar + 160 + q * 8) = zz;
        if (q == 0) *(u16x8*)(Ar + 192) = zz;
        stage16(node_vectors + (size_t)si * 96 + q * 24,      VS + me * KV + q * 24,      ve);
        stage8 (node_vectors + (size_t)si * 96 + q * 24 + 16, VS + me * KV + q * 24 + 16, ve);
        if (q == 0) Ar[160] = f2bf(ve ? lengths[eg] : 0.f);
    }
    __syncthreads();

    const int w  = t >> 6, l = t & 63;
    const int lr = l & 31;
    const int lg = l >> 5;
    const int m0 = (w >> 1) * 32;
    const int n0 = (w & 1) * 64;

    f32x16 acc0, acc1;
    const int n  = t & 127, ph = t >> 7;

    auto run_layer = [&](const u16* Asrc, int astr, const float* Wg, int Kr, int nsteps,
                         f32x16& a0, f32x16& a1) {
        #pragma unroll
        for (int i = 0; i < 16; ++i) { a0[i] = 0.f; a1[i] = 0.f; }
        #pragma unroll
        for (int i = 0; i < 4; ++i) {
            int kl = (i * 2 + ph) * 2;
            float v0 = (kl     < Kr) ? Wg[(size_t)kl * 128 + n]       : 0.f;
            float v1 = (kl + 1 < Kr) ? Wg[(size_t)(kl + 1) * 128 + n] : 0.f;
            unsigned pk = ((unsigned)f2bf(v1) << 16) | (unsigned)f2bf(v0);
            *(unsigned*)&Wt[0][n * WTS + kl] = pk;
        }
        __syncthreads();
        const u16* ap = Asrc + (m0 + lr) * astr + lg * 8;
        for (int ks = 0; ks < nsteps; ++ks) {
            const int cur = ks & 1;
            float v0[4], v1[4];
            const int kb = (ks + 1) * 16;
            if (ks + 1 < nsteps) {
                #pragma unroll
                for (int i = 0; i < 4; ++i) {
                    int kg = kb + (i * 2 + ph) * 2;
                    v0[i] = (kg     < Kr) ? Wg[(size_t)kg * 128 + n]       : 0.f;
                    v1[i] = (kg + 1 < Kr) ? Wg[(size_t)(kg + 1) * 128 + n] : 0.f;
                }
            }
            bf16x8 af = *(const bf16x8*)(ap + ks * 16);
            bf16x8 bf0 = *(const bf16x8*)(&Wt[cur][(n0      + lr) * WTS + lg * 8]);
            bf16x8 bf1 = *(const bf16x8*)(&Wt[cur][(n0 + 32 + lr) * WTS + lg * 8]);
            a0 = __builtin_amdgcn_mfma_f32_32x32x16_bf16(af, bf0, a0, 0, 0, 0);
            a1 = __builtin_amdgcn_mfma_f32_32x32x16_bf16(af, bf1, a1, 0, 0, 0);
            if (ks + 1 < nsteps) {
                #pragma unroll
                for (int i = 0; i < 4; ++i) {
                    int kl = (i * 2 + ph) * 2;
                    unsigned pk = ((unsigned)f2bf(v1[i]) << 16) | (unsigned)f2bf(v0[i]);
                    *(unsigned*)&Wt[cur ^ 1][n * WTS + kl] = pk;
                }
            }
            __syncthreads();
        }
    };

    run_layer(A, KP1, W1, 161, 11, acc0, acc1);
    {   const float bv0 = b1[n0 + lr], bv1 = b1[n0 + 32 + lr];
        #pragma unroll
        for (int r = 0; r < 16; ++r) {
            const int row = (r & 3) + 8 * (r >> 2) + 4 * lg;
            Hb[(m0 + row) * KH + n0 + lr]      = f2bf(fsilu(acc0[r] + bv0));
            Hb[(m0 + row) * KH + n0 + 32 + lr] = f2bf(fsilu(acc1[r] + bv1));
        }
    }
    __syncthreads();

    run_layer(Hb, KH, W2, 128, 8, acc0, acc1);
    __syncthreads();
    {   const float bv0 = b2[n0 + lr], bv1 = b2[n0 + 32 + lr];
        #pragma unroll
        for (int r = 0; r < 16; ++r) {
            const int row = (r & 3) + 8 * (r >> 2) + 4 * lg;
            Hb[(m0 + row) * KH + n0 + lr]      = f2bf(fsilu(acc0[r] + bv0));
            Hb[(m0 + row) * KH + n0 + 32 + lr] = f2bf(fsilu(acc1[r] + bv1));
        }
    }
    __syncthreads();

    run_layer(Hb, KH, W3, 128, 8, acc0, acc1);
    __syncthreads();
    {   const float bv0 = b3[n0 + lr], bv1 = b3[n0 + 32 + lr];
        #pragma unroll
        for (int r = 0; r < 16; ++r) {
            const int row = (r & 3) + 8 * (r >> 2) + 4 * lg;
            Hb[(m0 + row) * KH + n0 + lr]      = f2bf(acc0[r] + bv0);
            Hb[(m0 + row) * KH + n0 + 32 + lr] = f2bf(acc1[r] + bv1);
        }
    }
    __syncthreads();

    {   const int me = t >> 2, r = t & 3;
        const int eg2 = ebase + me;
        if (eg2 < N_EDGES) {
            const int row = ridx[me];
            const float evx = evl[0][me], evy = evl[1][me], evz = evl[2][me];
            float* orow = out + (size_t)row * OUTC;
            const u16* Ar = A  + me * KP1;
            const u16* Vr = VS + me * KV;
            const u16* Hr = Hb + me * KH;
            for (int col = r; col < OUTC; col += 4) {
                float val;
                if (col < 32) {
                    const int c = col;
                    const float vx = bf2f(Vr[3 * c]), vy = bf2f(Vr[3 * c + 1]), vz = bf2f(Vr[3 * c + 2]);
                    val = (vx * evx + vy * evy + vz * evz) * INV_SQ3 * bf2f(Hr[c]);
                } else {
                    const int idx = col - 32;
                    const int k = idx / 3;
                    const int d = idx - 3 * k;
                    const float g = bf2f(Hr[32 + k]);
                    if (k < 64) {
                        const float evd = (d == 0) ? evx : ((d == 1) ? evy : evz);
                        val = bf2f(Ar[k]) * evd * g;
                    } else {
                        const int c = k - 64;
                        const float vx = bf2f(Vr[3 * c]), vy = bf2f(Vr[3 * c + 1]), vz = bf2f(Vr[3 * c + 2]);
                        float cr;
                        if (d == 0)      cr = vy * evz - vz * evy;
                        else if (d == 1) cr = vz * evx - vx * evz;
                        else             cr = vx * evy - vy * evx;
                        val = cr * INV_SQ2 * g;
                    }
                }
                atomicAdd(&orow[col], val * INV_AVG);
            }
        }
    }
}

// ==================== launch ====================

extern "C" void kernel_launch(void* const* d_in, const int* in_sizes, int n_in,
                              void* d_out, int out_size, void* d_ws, size_t ws_size,
                              hipStream_t stream) {
    (void)in_sizes; (void)n_in;
    const float* node_scalars = (const float*)d_in[0];
    const float* node_vectors = (const float*)d_in[1];
    const float* edge_vec     = (const float*)d_in[2];
    const float* sef          = (const float*)d_in[3];
    const float* lengths      = (const float*)d_in[4];
    const int*   senders      = (const int*)d_in[5];
    const int*   receivers    = (const int*)d_in[6];
    const float* W1 = (const float*)d_in[7];
    const float* b1 = (const float*)d_in[8];
    const float* W2 = (const float*)d_in[9];
    const float* b2 = (const float*)d_in[10];
    const float* W3 = (const float*)d_in[11];
    const float* b3 = (const float*)d_in[12];
    float* out = (float*)d_out;

    // workspace layout (256B aligned slabs)
    auto align256 = [](size_t x) { return (x + 255) & ~(size_t)255; };
    size_t off = 0;
    const size_t o_mix     = off; off += align256((size_t)MIXROWS * 128 * sizeof(u16));
    const size_t o_counts  = off; off += align256((size_t)N_NODES * sizeof(int));
    const size_t o_rowp    = off; off += align256((size_t)(N_NODES + 1) * sizeof(int));
    const size_t o_cursors = off; off += align256((size_t)(N_NODES + 1) * sizeof(int));
    const size_t o_part    = off; off += align256(64 * sizeof(int));
    const size_t o_elist   = off; off += align256((size_t)N_EDGES * sizeof(int));
    const size_t ws_needed = off;

    const int nblk_e = (N_EDGES + EB - 1) / EB;

    if (ws_size >= ws_needed) {
        char* ws = (char*)d_ws;
        u16* mixws   = (u16*)(ws + o_mix);
        int* counts  = (int*)(ws + o_counts);
        int* rowp    = (int*)(ws + o_rowp);
        int* cursors = (int*)(ws + o_cursors);
        int* part    = (int*)(ws + o_part);
        int* elist   = (int*)(ws + o_elist);

        hipMemsetAsync(counts, 0, (size_t)N_NODES * sizeof(int), stream);
        hist_kernel<<<(N_EDGES + 255) / 256, 256, 0, stream>>>(receivers, counts);
        scan_k1<<<NBLK1, 256, 0, stream>>>(counts, rowp, part);
        scan_k2<<<1, 64, 0, stream>>>(part);
        scan_k3<<<NBLK1, 256, 0, stream>>>(rowp, part, cursors);
        fill_kernel<<<(N_EDGES + 255) / 256, 256, 0, stream>>>(receivers, cursors, elist);

        mlp_mix_kernel<<<nblk_e, 256, 0, stream>>>(
            node_scalars, sef, lengths, senders, receivers,
            W1, b1, W2, b2, W3, b3, mixws);

        node_gather_kernel<<<(N_NODES * 64 + 255) / 256, 256, 0, stream>>>(
            node_scalars, node_vectors, edge_vec, senders,
            rowp, elist, mixws, out);
    } else {
        hipMemsetAsync(out, 0, (size_t)out_size * sizeof(float), stream);
        fused_mpconv_atomic<<<nblk_e, 256, 0, stream>>>(
            node_scalars, node_vectors, edge_vec, sef, lengths,
            senders, receivers, W1, b1, W2, b2, W3, b3, out);
    }
}